// Round 6
// baseline (333.474 us; speedup 1.0000x reference)
//
#include <hip/hip_runtime.h>
#include <hip/hip_bf16.h>
#include <stdint.h>

// CausalMultiHeadAttention: B=4 S=2048 C=768 H=6 D=128
// cast(x,wT) -> GEMM1(LDS-tiled) -> V-transpose -> flash-attn(wave-level queue) -> GEMM2
#define SS 2048
#define CC 768
#define C3 2304
#define NITEMS (128 * 24)  // 16-row q-tiles x (b,h)

typedef float f32x4 __attribute__((ext_vector_type(4)));
typedef short s16x8 __attribute__((ext_vector_type(8)));

__device__ __forceinline__ unsigned short f2bf(float f) {
  union { float f; unsigned int u; } v; v.f = f;
  unsigned int r = (v.u + 0x7FFFu + ((v.u >> 16) & 1u)) >> 16;
  return (unsigned short)r;
}

__device__ __forceinline__ s16x8 ld8(const unsigned short* p) {
  return *reinterpret_cast<const s16x8*>(p);
}

__device__ __forceinline__ unsigned int cvt_pk_bf16(float lo, float hi) {
  unsigned int r;
  asm("v_cvt_pk_bf16_f32 %0, %1, %2" : "=v"(r) : "v"(lo), "v"(hi));
  return r;
}

__global__ __launch_bounds__(256) void cast_bf16_kernel(
    const float* __restrict__ src, unsigned short* __restrict__ dst, int n4) {
  int i = blockIdx.x * 256 + threadIdx.x;
  if (i < n4) {
    float4 v = reinterpret_cast<const float4*>(src)[i];
    ushort4 o;
    o.x = f2bf(v.x); o.y = f2bf(v.y); o.z = f2bf(v.z); o.w = f2bf(v.w);
    reinterpret_cast<ushort4*>(dst)[i] = o;
  }
}

// src [R][C] f32 -> dst [C][R] bf16
__global__ __launch_bounds__(256) void transpose_cast_kernel(
    const float* __restrict__ src, unsigned short* __restrict__ dst, int R, int C) {
  __shared__ float tile[32][33];
  int c0 = blockIdx.x * 32, r0 = blockIdx.y * 32;
  int tx = threadIdx.x & 31, ty = threadIdx.x >> 5;
  #pragma unroll
  for (int i = 0; i < 32; i += 8)
    tile[ty + i][tx] = src[(size_t)(r0 + ty + i) * C + c0 + tx];
  __syncthreads();
  #pragma unroll
  for (int i = 0; i < 32; i += 8)
    dst[(size_t)(c0 + ty + i) * R + r0 + tx] = f2bf(tile[tx][ty + i]);
}

// V region of qkv [token][C3] -> vT [bh][d=128][n=S], 64x128 tiles via swizzled LDS
__global__ __launch_bounds__(256) void vtrans_kernel(
    const unsigned short* __restrict__ qkv, unsigned short* __restrict__ vT) {
  __shared__ unsigned short t[64 * 128];
  const int tid = threadIdx.x;
  const int n0 = blockIdx.x * 64;
  const int bh = blockIdx.y;
  const int b = bh / 6, h = bh % 6;
  #pragma unroll
  for (int it = 0; it < 4; ++it) {
    int c = it * 256 + tid;
    int n = c >> 4, slot = c & 15;
    s16x8 v = ld8(qkv + (size_t)(b * SS + n0 + n) * C3 + 2 * CC + h * 128 + slot * 8);
    int ss = slot ^ ((n >> 3) & 7);
    *reinterpret_cast<s16x8*>(&t[n * 128 + ss * 8]) = v;
  }
  __syncthreads();
  #pragma unroll
  for (int it = 0; it < 4; ++it) {
    int c = it * 256 + tid;
    int d = c >> 3, n8 = (c & 7) * 8;
    s16x8 o;
    #pragma unroll
    for (int j = 0; j < 8; ++j) {
      int n = n8 + j;
      int sl = (d >> 3) ^ ((n >> 3) & 7);
      o[j] = (short)t[n * 128 + sl * 8 + (d & 7)];
    }
    *reinterpret_cast<s16x8*>(&vT[((size_t)bh * 128 + d) * SS + n0 + n8]) = o;
  }
}

// C[m][n] = sum_k A[m][k]*Bt[n][k] + bias[n].  128x128 tile, BK=32, LDS-staged.
template <int OUT_BF16>
__global__ __launch_bounds__(256) void gemm_lds_kernel(
    const unsigned short* __restrict__ A, const unsigned short* __restrict__ Bt,
    const float* __restrict__ bias, void* __restrict__ out, int M, int N, int K) {
  __shared__ unsigned short lA[128 * 32];
  __shared__ unsigned short lB[128 * 32];
  const int tid = threadIdx.x, lane = tid & 63, w = tid >> 6;
  const int m0 = blockIdx.y * 128, n0 = blockIdx.x * 128;
  const int lm = lane & 15, lg = lane >> 4;
  const int wm = (w >> 1) * 64, wn = (w & 1) * 64;
  const int rS = tid >> 2, sl = (tid & 3) * 8;
  const unsigned short* gA0 = A + (size_t)(m0 + rS) * K + sl;
  const unsigned short* gA1 = A + (size_t)(m0 + rS + 64) * K + sl;
  const unsigned short* gB0 = Bt + (size_t)(n0 + rS) * K + sl;
  const unsigned short* gB1 = Bt + (size_t)(n0 + rS + 64) * K + sl;
  unsigned short* dA0 = &lA[tid * 8];
  unsigned short* dA1 = &lA[(tid + 256) * 8];
  unsigned short* dB0 = &lB[tid * 8];
  unsigned short* dB1 = &lB[(tid + 256) * 8];
  int aOff[4], bOff[4];
  #pragma unroll
  for (int i = 0; i < 4; ++i) {
    aOff[i] = (wm + i * 16 + lm) * 32 + lg * 8;
    bOff[i] = (wn + i * 16 + lm) * 32 + lg * 8;
  }
  f32x4 acc[4][4] = {};
  for (int k0 = 0; k0 < K; k0 += 32) {
    s16x8 ra0 = ld8(gA0 + k0), ra1 = ld8(gA1 + k0);
    s16x8 rb0 = ld8(gB0 + k0), rb1 = ld8(gB1 + k0);
    __syncthreads();
    *reinterpret_cast<s16x8*>(dA0) = ra0;
    *reinterpret_cast<s16x8*>(dA1) = ra1;
    *reinterpret_cast<s16x8*>(dB0) = rb0;
    *reinterpret_cast<s16x8*>(dB1) = rb1;
    __syncthreads();
    s16x8 af[4], bf[4];
    #pragma unroll
    for (int i = 0; i < 4; ++i) af[i] = ld8(&lA[aOff[i]]);
    #pragma unroll
    for (int i = 0; i < 4; ++i) bf[i] = ld8(&lB[bOff[i]]);
    #pragma unroll
    for (int mi = 0; mi < 4; ++mi)
      #pragma unroll
      for (int ni = 0; ni < 4; ++ni)
        acc[mi][ni] = __builtin_amdgcn_mfma_f32_16x16x32_bf16(af[mi], bf[ni], acc[mi][ni], 0, 0, 0);
  }
  #pragma unroll
  for (int mi = 0; mi < 4; ++mi) {
    #pragma unroll
    for (int ni = 0; ni < 4; ++ni) {
      const int row = m0 + wm + mi * 16 + lg * 4;
      const int col = n0 + wn + ni * 16 + lm;
      const float bs = bias[col];
      #pragma unroll
      for (int r = 0; r < 4; ++r) {
        float v = acc[mi][ni][r] + bs;
        if (OUT_BF16)
          ((unsigned short*)out)[(size_t)(row + r) * N + col] = f2bf(v);
        else
          ((float*)out)[(size_t)(row + r) * N + col] = v;
      }
    }
  }
}

// Flash attention, causal. WAVE-level dynamic queue: item = (bh, 16-row q-tile),
// LPT (high q-tiles first). Each wave fully independent — no barriers at all.
// KVBLK=64. K direct from global; V^T direct from pre-transposed vT.
__global__ __launch_bounds__(256) void attn_kernel(
    const unsigned short* __restrict__ qkv,
    const unsigned short* __restrict__ vT,
    unsigned short* __restrict__ aout,
    int* __restrict__ ctr) {
  const int tid = threadIdx.x, lane = tid & 63, w = tid >> 6;
  const int lm = lane & 15, lg = lane >> 4;
  __shared__ unsigned int pb[4][16 * 44];  // per-wave P rows, u32 stride 44
  const float scale = 0.08838834764831845f;  // 1/sqrt(128)
  unsigned int* pr = &pb[w][lm * 44];
  for (;;) {
    int item;
    if (lane == 0) item = atomicAdd(ctr, 1);
    item = __shfl(item, 0);
    if (item >= NITEMS) return;
    const int qt = 127 - (item / 24);  // expensive q-tiles first (LPT)
    const int bh = item % 24;
    const int b = bh / 6, h = bh % 6;
    const int wq0 = qt * 16;
    const unsigned short* base = qkv + (size_t)b * SS * C3;
    const unsigned short* kbase = base + CC + h * 128;
    const unsigned short* vb = vT + (size_t)bh * 128 * SS;
    s16x8 qf[4];
    {
      const unsigned short* qp = base + (size_t)(wq0 + lm) * C3 + h * 128 + lg * 8;
      #pragma unroll
      for (int ks = 0; ks < 4; ++ks) qf[ks] = ld8(qp + ks * 32);
    }
    f32x4 oacc[8] = {};
    float m_run = -1e30f, l_run = 0.0f;
    for (int n0 = 0; n0 < wq0 + 16; n0 += 64) {
      // QK^T swapped: sacc[nsub] = S^T[n][q], n = n0+nsub*16+lg*4+r, q = lm
      f32x4 sacc[4] = {};
      #pragma unroll
      for (int nsub = 0; nsub < 4; ++nsub) {
        const unsigned short* kp = kbase + (size_t)(n0 + nsub * 16 + lm) * C3 + lg * 8;
        #pragma unroll
        for (int ks = 0; ks < 4; ++ks)
          sacc[nsub] = __builtin_amdgcn_mfma_f32_16x16x32_bf16(ld8(kp + ks * 32), qf[ks], sacc[nsub], 0, 0, 0);
      }
      const int qg = wq0 + lm;
      const bool full = (n0 + 63 <= wq0);
      float xs[4][4];
      float tmax = -1e30f;
      #pragma unroll
      for (int nsub = 0; nsub < 4; ++nsub) {
        #pragma unroll
        for (int r = 0; r < 4; ++r) {
          int n = n0 + nsub * 16 + lg * 4 + r;
          float x = sacc[nsub][r] * scale;
          if (!full && n > qg) x = -1e30f;
          xs[nsub][r] = x;
          tmax = fmaxf(tmax, x);
        }
      }
      tmax = fmaxf(tmax, __shfl_xor(tmax, 16));
      tmax = fmaxf(tmax, __shfl_xor(tmax, 32));
      const float m_new = fmaxf(m_run, tmax);
      float psum = 0.0f;
      unsigned int pk_[4][2];
      #pragma unroll
      for (int nsub = 0; nsub < 4; ++nsub) {
        float p0 = __expf(xs[nsub][0] - m_new);
        float p1 = __expf(xs[nsub][1] - m_new);
        float p2 = __expf(xs[nsub][2] - m_new);
        float p3 = __expf(xs[nsub][3] - m_new);
        psum += (p0 + p1) + (p2 + p3);
        pk_[nsub][0] = cvt_pk_bf16(p0, p1);
        pk_[nsub][1] = cvt_pk_bf16(p2, p3);
      }
      psum += __shfl_xor(psum, 16);
      psum += __shfl_xor(psum, 32);
      const float resc = __expf(m_run - m_new);
      l_run = l_run * resc + psum;
      m_run = m_new;
      float rs[4];
      #pragma unroll
      for (int r = 0; r < 4; ++r) rs[r] = __shfl(resc, lg * 4 + r);
      #pragma unroll
      for (int dsub = 0; dsub < 8; ++dsub)
        #pragma unroll
        for (int r = 0; r < 4; ++r) oacc[dsub][r] *= rs[r];
      // stage P^T -> P rows in per-wave LDS (u32 pairs; row q=lm, cols n)
      #pragma unroll
      for (int nsub = 0; nsub < 4; ++nsub) {
        pr[nsub * 8 + lg * 2] = pk_[nsub][0];
        pr[nsub * 8 + lg * 2 + 1] = pk_[nsub][1];
      }
      // PV: A = P[q=lm][n-chunk], B = V^T direct from global (coalesced b128)
      #pragma unroll
      for (int nch = 0; nch < 2; ++nch) {
        s16x8 pf = *reinterpret_cast<const s16x8*>(&pr[nch * 16 + lg * 4]);
        const unsigned short* vp0 = vb + (size_t)lm * SS + n0 + nch * 32 + lg * 8;
        #pragma unroll
        for (int dsub = 0; dsub < 8; ++dsub) {
          s16x8 vf = ld8(vp0 + (size_t)dsub * 16 * SS);
          oacc[dsub] = __builtin_amdgcn_mfma_f32_16x16x32_bf16(pf, vf, oacc[dsub], 0, 0, 0);
        }
      }
    }
    float linv[4];
    #pragma unroll
    for (int r = 0; r < 4; ++r) linv[r] = 1.0f / __shfl(l_run, lg * 4 + r);
    #pragma unroll
    for (int dsub = 0; dsub < 8; ++dsub) {
      const int col = h * 128 + dsub * 16 + lm;
      #pragma unroll
      for (int r = 0; r < 4; ++r)
        aout[(size_t)(b * SS + wq0 + lg * 4 + r) * CC + col] =
            f2bf(oacc[dsub][r] * linv[r]);
    }
  }
}

extern "C" void kernel_launch(void* const* d_in, const int* in_sizes, int n_in,
                              void* d_out, int out_size, void* d_ws, size_t ws_size,
                              hipStream_t stream) {
  const float* x      = (const float*)d_in[0];
  const float* w_attn = (const float*)d_in[1];
  const float* b_attn = (const float*)d_in[2];
  const float* w_proj = (const float*)d_in[3];
  const float* b_proj = (const float*)d_in[4];
  float* out = (float*)d_out;

  const size_t M = 4 * (size_t)SS;  // 8192 tokens
  unsigned short* ws = (unsigned short*)d_ws;
  unsigned short* xb   = ws;                        // [8192,768] (dead after GEMM1)
  unsigned short* waT  = xb + M * CC;               // [2304,768]
  unsigned short* wpT  = waT + (size_t)C3 * CC;     // [768,768]
  unsigned short* qkv  = wpT + (size_t)CC * CC;     // [8192,2304]
  unsigned short* aout = qkv + M * C3;              // [8192,768]
  unsigned short* vT   = xb;                        // [24,128,2048] aliases dead xb
  int* ctr = (int*)(aout + M * CC);

  int n4 = (int)(M * CC / 4);
  cast_bf16_kernel<<<(n4 + 255) / 256, 256, 0, stream>>>(x, xb, n4);
  transpose_cast_kernel<<<dim3(C3 / 32, CC / 32), 256, 0, stream>>>(w_attn, waT, CC, C3);
  transpose_cast_kernel<<<dim3(CC / 32, CC / 32), 256, 0, stream>>>(w_proj, wpT, CC, CC);

  gemm_lds_kernel<1><<<dim3(C3 / 128, M / 128), 256, 0, stream>>>(
      xb, waT, b_attn, (void*)qkv, (int)M, C3, CC);

  vtrans_kernel<<<dim3(SS / 64, 24), 256, 0, stream>>>(qkv, vT);

  hipMemsetAsync(ctr, 0, sizeof(int), stream);
  attn_kernel<<<768, 256, 0, stream>>>(qkv, vT, aout, ctr);

  gemm_lds_kernel<0><<<dim3(CC / 128, M / 128), 256, 0, stream>>>(
      aout, wpT, b_proj, (void*)out, (int)M, CC, CC);
}

// Round 7
// 199.851 us; speedup vs baseline: 1.6686x; 1.6686x over previous
//
#include <hip/hip_runtime.h>
#include <hip/hip_bf16.h>
#include <stdint.h>

// CausalMultiHeadAttention: B=4 S=2048 C=768 H=6 D=128
// cast(x,wT) -> GEMM1(gload_lds dbuf) -> V-transpose -> flash-attn(block queue,
// K+V double-buffered LDS via global_load_lds, swizzled) -> GEMM2
#define SS 2048
#define CC 768
#define C3 2304
#define NITEMS (32 * 24)  // 64-row q-tiles x (b,h)

typedef float f32x4 __attribute__((ext_vector_type(4)));
typedef short s16x8 __attribute__((ext_vector_type(8)));

__device__ __forceinline__ unsigned short f2bf(float f) {
  union { float f; unsigned int u; } v; v.f = f;
  unsigned int r = (v.u + 0x7FFFu + ((v.u >> 16) & 1u)) >> 16;
  return (unsigned short)r;
}

__device__ __forceinline__ s16x8 ld8(const unsigned short* p) {
  return *reinterpret_cast<const s16x8*>(p);
}

__device__ __forceinline__ unsigned int cvt_pk_bf16(float lo, float hi) {
  unsigned int r;
  asm("v_cvt_pk_bf16_f32 %0, %1, %2" : "=v"(r) : "v"(lo), "v"(hi));
  return r;
}

// async global->LDS, 16B/lane. LDS dest = wave-uniform base + lane*16 (linear);
// per-lane global src carries any swizzle (guide §5 caveat, rule #21).
__device__ __forceinline__ void gload_lds16(const unsigned short* g, unsigned short* l) {
  __builtin_amdgcn_global_load_lds(
      (const __attribute__((address_space(1))) void*)g,
      (__attribute__((address_space(3))) void*)l, 16, 0, 0);
}

__global__ __launch_bounds__(256) void cast_bf16_kernel(
    const float* __restrict__ src, unsigned short* __restrict__ dst, int n4) {
  int i = blockIdx.x * 256 + threadIdx.x;
  if (i < n4) {
    float4 v = reinterpret_cast<const float4*>(src)[i];
    ushort4 o;
    o.x = f2bf(v.x); o.y = f2bf(v.y); o.z = f2bf(v.z); o.w = f2bf(v.w);
    reinterpret_cast<ushort4*>(dst)[i] = o;
  }
}

// src [R][C] f32 -> dst [C][R] bf16
__global__ __launch_bounds__(256) void transpose_cast_kernel(
    const float* __restrict__ src, unsigned short* __restrict__ dst, int R, int C) {
  __shared__ float tile[32][33];
  int c0 = blockIdx.x * 32, r0 = blockIdx.y * 32;
  int tx = threadIdx.x & 31, ty = threadIdx.x >> 5;
  #pragma unroll
  for (int i = 0; i < 32; i += 8)
    tile[ty + i][tx] = src[(size_t)(r0 + ty + i) * C + c0 + tx];
  __syncthreads();
  #pragma unroll
  for (int i = 0; i < 32; i += 8)
    dst[(size_t)(c0 + ty + i) * R + r0 + tx] = f2bf(tile[tx][ty + i]);
}

// V region of qkv [token][C3] -> vT [bh][d=128][n=S], 64x128 tiles via swizzled LDS
__global__ __launch_bounds__(256) void vtrans_kernel(
    const unsigned short* __restrict__ qkv, unsigned short* __restrict__ vT) {
  __shared__ unsigned short t[64 * 128];
  const int tid = threadIdx.x;
  const int n0 = blockIdx.x * 64;
  const int bh = blockIdx.y;
  const int b = bh / 6, h = bh % 6;
  #pragma unroll
  for (int it = 0; it < 4; ++it) {
    int c = it * 256 + tid;
    int n = c >> 4, slot = c & 15;
    s16x8 v = ld8(qkv + (size_t)(b * SS + n0 + n) * C3 + 2 * CC + h * 128 + slot * 8);
    int ss = slot ^ ((n >> 3) & 7);
    *reinterpret_cast<s16x8*>(&t[n * 128 + ss * 8]) = v;
  }
  __syncthreads();
  #pragma unroll
  for (int it = 0; it < 4; ++it) {
    int c = it * 256 + tid;
    int d = c >> 3, n8 = (c & 7) * 8;
    s16x8 o;
    #pragma unroll
    for (int j = 0; j < 8; ++j) {
      int n = n8 + j;
      int sl = (d >> 3) ^ ((n >> 3) & 7);
      o[j] = (short)t[n * 128 + sl * 8 + (d & 7)];
    }
    *reinterpret_cast<s16x8*>(&vT[((size_t)bh * 128 + d) * SS + n0 + n8]) = o;
  }
}

// C[m][n] = sum_k A[m][k]*Bt[n][k] + bias[n]. 128x128 tile, BK=32.
// Double-buffered LDS staged via global_load_lds (linear layout; reads are
// conflict-free: 64B rows wrap banks every 2 rows). One barrier per K-step.
template <int OUT_BF16>
__global__ __launch_bounds__(256) void gemm_lds_kernel(
    const unsigned short* __restrict__ A, const unsigned short* __restrict__ Bt,
    const float* __restrict__ bias, void* __restrict__ out, int M, int N, int K) {
  __shared__ unsigned short lA[2][128 * 32];
  __shared__ unsigned short lB[2][128 * 32];
  const int tid = threadIdx.x, lane = tid & 63, w = tid >> 6;
  const int m0 = blockIdx.y * 128, n0 = blockIdx.x * 128;
  const int lm = lane & 15, lg = lane >> 4;
  const int wm = (w >> 1) * 64, wn = (w & 1) * 64;
  // staging: chunk c (1KB = 16 rows x 64B); wave w owns chunks {2w, 2w+1} of A and B.
  const int sr = lane >> 2, ssl = (lane & 3) * 8;  // row-in-chunk, elem offset
  int aOff[4], bOff[4];
  #pragma unroll
  for (int i = 0; i < 4; ++i) {
    aOff[i] = (wm + i * 16 + lm) * 32 + lg * 8;
    bOff[i] = (wn + i * 16 + lm) * 32 + lg * 8;
  }
  f32x4 acc[4][4] = {};
  const int nt = K / 32;
  #pragma unroll 1
  for (int t = -1; t < nt; ++t) {
    if (t + 1 < nt) {
      const int k0 = (t + 1) * 32;
      const int cs = (t + 1) & 1;
      #pragma unroll
      for (int i = 0; i < 2; ++i) {
        int c = w * 2 + i;
        int row = c * 16 + sr;
        gload_lds16(A + (size_t)(m0 + row) * K + k0 + ssl, &lA[cs][c * 512]);
        gload_lds16(Bt + (size_t)(n0 + row) * K + k0 + ssl, &lB[cs][c * 512]);
      }
    }
    if (t >= 0) {
      const int cu = t & 1;
      s16x8 af[4], bf[4];
      #pragma unroll
      for (int i = 0; i < 4; ++i) af[i] = ld8(&lA[cu][aOff[i]]);
      #pragma unroll
      for (int i = 0; i < 4; ++i) bf[i] = ld8(&lB[cu][bOff[i]]);
      #pragma unroll
      for (int mi = 0; mi < 4; ++mi)
        #pragma unroll
        for (int ni = 0; ni < 4; ++ni)
          acc[mi][ni] = __builtin_amdgcn_mfma_f32_16x16x32_bf16(af[mi], bf[ni], acc[mi][ni], 0, 0, 0);
    }
    __syncthreads();  // drains vmcnt (tile t+1 landed) + guards buffer reuse
  }
  #pragma unroll
  for (int mi = 0; mi < 4; ++mi) {
    #pragma unroll
    for (int ni = 0; ni < 4; ++ni) {
      const int row = m0 + wm + mi * 16 + lg * 4;
      const int col = n0 + wn + ni * 16 + lm;
      const float bs = bias[col];
      #pragma unroll
      for (int r = 0; r < 4; ++r) {
        float v = acc[mi][ni][r] + bs;
        if (OUT_BF16)
          ((unsigned short*)out)[(size_t)(row + r) * N + col] = f2bf(v);
        else
          ((float*)out)[(size_t)(row + r) * N + col] = v;
      }
    }
  }
}

// Flash attention, causal. Block-level queue: item = (bh, 64-row q-tile), LPT.
// 4 waves/block share the item; K and V tiles (64 kv-rows) double-buffered in
// LDS, staged with global_load_lds using inverse-swizzled global sources
// (slot ^= row&7) so swizzled ds_read_b128 frags are conflict-free.
__global__ __launch_bounds__(256) void attn_kernel(
    const unsigned short* __restrict__ qkv,
    const unsigned short* __restrict__ vT,
    unsigned short* __restrict__ aout,
    int* __restrict__ ctr) {
  const int tid = threadIdx.x, lane = tid & 63, w = tid >> 6;
  const int lm = lane & 15, lg = lane >> 4;
  __shared__ unsigned short kbuf[2][64 * 128];  // [kv-row][128 elems], slot-swizzled
  __shared__ unsigned short vbuf[2][128 * 64];  // [d][64 n-elems], slot-swizzled
  __shared__ unsigned int pb[4][16 * 44];       // per-wave P rows, u32 stride 44
  __shared__ int s_item;
  const float scale = 0.08838834764831845f;  // 1/sqrt(128)
  unsigned int* pr = &pb[w][lm * 44];
  // staging lane decomposition
  const int klg4 = lane >> 4, ks16 = lane & 15;  // K: row-in-4, 16B slot (16/row)
  const int vlg8 = lane >> 3, vs8 = lane & 7;    // V: d-in-8,   16B slot (8/row)
  for (;;) {
    __syncthreads();
    if (tid == 0) s_item = atomicAdd(ctr, 1);
    __syncthreads();
    const int item = s_item;
    if (item >= NITEMS) return;
    const int qt = 31 - (item / 24);  // expensive q-tiles first (LPT)
    const int bh = item % 24;
    const int b = bh / 6, h = bh % 6;
    const int q0 = qt * 64, wq0 = q0 + w * 16;
    const unsigned short* base = qkv + (size_t)b * SS * C3;
    const unsigned short* kg = base + CC + h * 128;
    const unsigned short* vg = vT + (size_t)bh * 128 * SS;
    s16x8 qf[4];
    {
      const unsigned short* qp = base + (size_t)(wq0 + lm) * C3 + h * 128 + lg * 8;
      #pragma unroll
      for (int ks = 0; ks < 4; ++ks) qf[ks] = ld8(qp + ks * 32);
    }
    f32x4 oacc[8] = {};
    float m_run = -1e30f, l_run = 0.0f;
    const int nt = qt + 1;  // 64-wide kv tiles
    #pragma unroll 1
    for (int t = -1; t < nt; ++t) {
      if (t + 1 < nt) {  // stage tile t+1 (K rows + V^T rows), inverse-swizzled src
        const int n1 = (t + 1) * 64;
        const int cs = (t + 1) & 1;
        #pragma unroll
        for (int i = 0; i < 4; ++i) {
          int c = w * 4 + i;
          int r = c * 4 + klg4;
          gload_lds16(kg + (size_t)(n1 + r) * C3 + ((ks16 ^ (r & 7)) * 8),
                      &kbuf[cs][c * 512]);
        }
        #pragma unroll
        for (int i = 0; i < 4; ++i) {
          int c = w * 4 + i;
          int d = c * 8 + vlg8;
          gload_lds16(vg + (size_t)d * SS + n1 + ((vs8 ^ vlg8) * 8),
                      &vbuf[cs][c * 512]);
        }
      }
      if (t >= 0 && t * 64 <= wq0 + 15) {
        const int n0 = t * 64;
        const int cu = t & 1;
        const unsigned short* kb = kbuf[cu];
        const unsigned short* vb = vbuf[cu];
        // QK^T swapped: sacc[nsub] = S^T[n][q], n = n0+nsub*16+lg*4+r, q = lm
        f32x4 sacc[4] = {};
        #pragma unroll
        for (int nsub = 0; nsub < 4; ++nsub) {
          const int kr = (nsub * 16 + lm) * 128;
          #pragma unroll
          for (int ks = 0; ks < 4; ++ks) {
            s16x8 kf = ld8(&kb[kr + (((ks * 4 + lg) ^ (lm & 7)) * 8)]);
            sacc[nsub] = __builtin_amdgcn_mfma_f32_16x16x32_bf16(kf, qf[ks], sacc[nsub], 0, 0, 0);
          }
        }
        const int qg = wq0 + lm;
        const bool full = (n0 + 63 <= wq0);
        float xs[4][4];
        float tmax = -1e30f;
        #pragma unroll
        for (int nsub = 0; nsub < 4; ++nsub) {
          #pragma unroll
          for (int r = 0; r < 4; ++r) {
            int n = n0 + nsub * 16 + lg * 4 + r;
            float x = sacc[nsub][r] * scale;
            if (!full && n > qg) x = -1e30f;
            xs[nsub][r] = x;
            tmax = fmaxf(tmax, x);
          }
        }
        tmax = fmaxf(tmax, __shfl_xor(tmax, 16));
        tmax = fmaxf(tmax, __shfl_xor(tmax, 32));
        const float m_new = fmaxf(m_run, tmax);
        float psum = 0.0f;
        unsigned int pk_[4][2];
        #pragma unroll
        for (int nsub = 0; nsub < 4; ++nsub) {
          float p0 = __expf(xs[nsub][0] - m_new);
          float p1 = __expf(xs[nsub][1] - m_new);
          float p2 = __expf(xs[nsub][2] - m_new);
          float p3 = __expf(xs[nsub][3] - m_new);
          psum += (p0 + p1) + (p2 + p3);
          pk_[nsub][0] = cvt_pk_bf16(p0, p1);
          pk_[nsub][1] = cvt_pk_bf16(p2, p3);
        }
        psum += __shfl_xor(psum, 16);
        psum += __shfl_xor(psum, 32);
        const float resc = __expf(m_run - m_new);
        l_run = l_run * resc + psum;
        m_run = m_new;
        float rs[4];
        #pragma unroll
        for (int r = 0; r < 4; ++r) rs[r] = __shfl(resc, lg * 4 + r);
        #pragma unroll
        for (int dsub = 0; dsub < 8; ++dsub)
          #pragma unroll
          for (int r = 0; r < 4; ++r) oacc[dsub][r] *= rs[r];
        // stage P^T -> P rows in per-wave LDS (u32 pairs; row q=lm, cols n)
        #pragma unroll
        for (int nsub = 0; nsub < 4; ++nsub) {
          pr[nsub * 8 + lg * 2] = pk_[nsub][0];
          pr[nsub * 8 + lg * 2 + 1] = pk_[nsub][1];
        }
        // PV: A = P[q=lm][n-chunk], B = V^T frags from swizzled LDS
        #pragma unroll
        for (int nch = 0; nch < 2; ++nch) {
          s16x8 pf = *reinterpret_cast<const s16x8*>(&pr[nch * 16 + lg * 4]);
          #pragma unroll
          for (int dsub = 0; dsub < 8; ++dsub) {
            const int vr = (dsub * 16 + lm) * 64;
            s16x8 vf = ld8(&vb[vr + (((nch * 4 + lg) ^ (lm & 7)) * 8)]);
            oacc[dsub] = __builtin_amdgcn_mfma_f32_16x16x32_bf16(pf, vf, oacc[dsub], 0, 0, 0);
          }
        }
      }
      __syncthreads();  // drains vmcnt (tile t+1 landed) + guards buffer reuse
    }
    float linv[4];
    #pragma unroll
    for (int r = 0; r < 4; ++r) linv[r] = 1.0f / __shfl(l_run, lg * 4 + r);
    #pragma unroll
    for (int dsub = 0; dsub < 8; ++dsub) {
      const int col = h * 128 + dsub * 16 + lm;
      #pragma unroll
      for (int r = 0; r < 4; ++r)
        aout[(size_t)(b * SS + wq0 + lg * 4 + r) * CC + col] =
            f2bf(oacc[dsub][r] * linv[r]);
    }
  }
}

extern "C" void kernel_launch(void* const* d_in, const int* in_sizes, int n_in,
                              void* d_out, int out_size, void* d_ws, size_t ws_size,
                              hipStream_t stream) {
  const float* x      = (const float*)d_in[0];
  const float* w_attn = (const float*)d_in[1];
  const float* b_attn = (const float*)d_in[2];
  const float* w_proj = (const float*)d_in[3];
  const float* b_proj = (const float*)d_in[4];
  float* out = (float*)d_out;

  const size_t M = 4 * (size_t)SS;  // 8192 tokens
  unsigned short* ws = (unsigned short*)d_ws;
  unsigned short* xb   = ws;                        // [8192,768] (dead after GEMM1)
  unsigned short* waT  = xb + M * CC;               // [2304,768]
  unsigned short* wpT  = waT + (size_t)C3 * CC;     // [768,768]
  unsigned short* qkv  = wpT + (size_t)CC * CC;     // [8192,2304]
  unsigned short* aout = qkv + M * C3;              // [8192,768]
  unsigned short* vT   = xb;                        // [24,128,2048] aliases dead xb
  int* ctr = (int*)(aout + M * CC);

  int n4 = (int)(M * CC / 4);
  cast_bf16_kernel<<<(n4 + 255) / 256, 256, 0, stream>>>(x, xb, n4);
  transpose_cast_kernel<<<dim3(C3 / 32, CC / 32), 256, 0, stream>>>(w_attn, waT, CC, C3);
  transpose_cast_kernel<<<dim3(CC / 32, CC / 32), 256, 0, stream>>>(w_proj, wpT, CC, CC);

  gemm_lds_kernel<1><<<dim3(C3 / 128, M / 128), 256, 0, stream>>>(
      xb, waT, b_attn, (void*)qkv, (int)M, C3, CC);

  vtrans_kernel<<<dim3(SS / 64, 24), 256, 0, stream>>>(qkv, vT);

  hipMemsetAsync(ctr, 0, sizeof(int), stream);
  attn_kernel<<<512, 256, 0, stream>>>(qkv, vT, aout, ctr);

  gemm_lds_kernel<0><<<dim3(CC / 128, M / 128), 256, 0, stream>>>(
      aout, wpT, b_proj, (void*)out, (int)M, CC, CC);
}

// Round 9
// 195.379 us; speedup vs baseline: 1.7068x; 1.0229x over previous
//
#include <hip/hip_runtime.h>
#include <hip/hip_bf16.h>
#include <stdint.h>

// CausalMultiHeadAttention: B=4 S=2048 C=768 H=6 D=128
// cast(x,wT) -> GEMM1(dbuf LDS, swizzled, XCD-swizzled grid) -> V-transpose ->
// flash-attn(block queue, dbuf LDS, setprio, defer-max) -> GEMM2
#define SS 2048
#define CC 768
#define C3 2304
#define NITEMS (32 * 24)  // 64-row q-tiles x (b,h)

typedef float f32x4 __attribute__((ext_vector_type(4)));
typedef short s16x8 __attribute__((ext_vector_type(8)));

__device__ __forceinline__ unsigned short f2bf(float f) {
  union { float f; unsigned int u; } v; v.f = f;
  unsigned int r = (v.u + 0x7FFFu + ((v.u >> 16) & 1u)) >> 16;
  return (unsigned short)r;
}

__device__ __forceinline__ s16x8 ld8(const unsigned short* p) {
  return *reinterpret_cast<const s16x8*>(p);
}

__device__ __forceinline__ unsigned int cvt_pk_bf16(float lo, float hi) {
  unsigned int r;
  asm("v_cvt_pk_bf16_f32 %0, %1, %2" : "=v"(r) : "v"(lo), "v"(hi));
  return r;
}

// async global->LDS, 16B/lane. LDS dest = wave-uniform base + lane*16 (linear);
// per-lane global src carries the swizzle (rule #21: linear dest + inv-swz src).
__device__ __forceinline__ void gload_lds16(const unsigned short* g, unsigned short* l) {
  __builtin_amdgcn_global_load_lds(
      (const __attribute__((address_space(1))) void*)g,
      (__attribute__((address_space(3))) void*)l, 16, 0, 0);
}

__global__ __launch_bounds__(256) void cast_bf16_kernel(
    const float* __restrict__ src, unsigned short* __restrict__ dst, int n4) {
  int i = blockIdx.x * 256 + threadIdx.x;
  if (i < n4) {
    float4 v = reinterpret_cast<const float4*>(src)[i];
    ushort4 o;
    o.x = f2bf(v.x); o.y = f2bf(v.y); o.z = f2bf(v.z); o.w = f2bf(v.w);
    reinterpret_cast<ushort4*>(dst)[i] = o;
  }
}

// src [R][C] f32 -> dst [C][R] bf16
__global__ __launch_bounds__(256) void transpose_cast_kernel(
    const float* __restrict__ src, unsigned short* __restrict__ dst, int R, int C) {
  __shared__ float tile[32][33];
  int c0 = blockIdx.x * 32, r0 = blockIdx.y * 32;
  int tx = threadIdx.x & 31, ty = threadIdx.x >> 5;
  #pragma unroll
  for (int i = 0; i < 32; i += 8)
    tile[ty + i][tx] = src[(size_t)(r0 + ty + i) * C + c0 + tx];
  __syncthreads();
  #pragma unroll
  for (int i = 0; i < 32; i += 8)
    dst[(size_t)(c0 + ty + i) * R + r0 + tx] = f2bf(tile[tx][ty + i]);
}

// V region of qkv [token][C3] -> vT [bh][d=128][n=S], 64x128 tiles via swizzled LDS
__global__ __launch_bounds__(256) void vtrans_kernel(
    const unsigned short* __restrict__ qkv, unsigned short* __restrict__ vT) {
  __shared__ unsigned short t[64 * 128];
  const int tid = threadIdx.x;
  const int n0 = blockIdx.x * 64;
  const int bh = blockIdx.y;
  const int b = bh / 6, h = bh % 6;
  #pragma unroll
  for (int it = 0; it < 4; ++it) {
    int c = it * 256 + tid;
    int n = c >> 4, slot = c & 15;
    s16x8 v = ld8(qkv + (size_t)(b * SS + n0 + n) * C3 + 2 * CC + h * 128 + slot * 8);
    int ss = slot ^ ((n >> 3) & 7);
    *reinterpret_cast<s16x8*>(&t[n * 128 + ss * 8]) = v;
  }
  __syncthreads();
  #pragma unroll
  for (int it = 0; it < 4; ++it) {
    int c = it * 256 + tid;
    int d = c >> 3, n8 = (c & 7) * 8;
    s16x8 o;
    #pragma unroll
    for (int j = 0; j < 8; ++j) {
      int n = n8 + j;
      int sl = (d >> 3) ^ ((n >> 3) & 7);
      o[j] = (short)t[n * 128 + sl * 8 + (d & 7)];
    }
    *reinterpret_cast<s16x8*>(&vT[((size_t)bh * 128 + d) * SS + n0 + n8]) = o;
  }
}

// C[m][n] = sum_k A[m][k]*Bt[n][k] + bias[n]. 128x128 tile, BK=32.
// 2-buffer LDS pipeline: stage(t+1) issued, compute(t), __syncthreads (full
// drain — depth-1, immune to vmcnt miscount). Frag reads conflict-free via
// XOR swizzle slot ^= (row>>1)&3 on BOTH gload source and ds_read addr (#21).
template <int OUT_BF16>
__global__ __launch_bounds__(256) void gemm_lds_kernel(
    const unsigned short* __restrict__ A, const unsigned short* __restrict__ Bt,
    const float* __restrict__ bias, void* __restrict__ out, int M, int N, int K) {
  __shared__ unsigned short lA[2][128 * 32];
  __shared__ unsigned short lB[2][128 * 32];
  const int tid = threadIdx.x, lane = tid & 63, w = tid >> 6;
  // XCD-bijective swizzle (nwg % 8 == 0 for all our grids)
  const int nbx = gridDim.x;
  int bid = blockIdx.y * nbx + blockIdx.x;
  const int cpx = (nbx * gridDim.y) >> 3;
  bid = (bid & 7) * cpx + (bid >> 3);
  const int m0 = (bid / nbx) * 128, n0 = (bid % nbx) * 128;
  const int lm = lane & 15, lg = lane >> 4;
  const int wm = (w >> 1) * 64, wn = (w & 1) * 64;
  const int sr = lane >> 2;                            // row-in-chunk 0..15
  const int ssl = ((lane & 3) ^ ((sr >> 1) & 3)) * 8;  // inv-swizzled k-slot
  int aOff[4], bOff[4];
  #pragma unroll
  for (int i = 0; i < 4; ++i) {
    int ra = wm + i * 16 + lm, rb = wn + i * 16 + lm;
    aOff[i] = ra * 32 + ((lg ^ ((ra >> 1) & 3)) * 8);
    bOff[i] = rb * 32 + ((lg ^ ((rb >> 1) & 3)) * 8);
  }
  f32x4 acc[4][4] = {};
  const int nt = K / 32;
  #pragma unroll 1
  for (int t = -1; t < nt; ++t) {
    if (t + 1 < nt) {
      const int k0 = (t + 1) * 32;
      const int cs = (t + 1) & 1;
      #pragma unroll
      for (int i = 0; i < 2; ++i) {
        int c = w * 2 + i;
        int row = c * 16 + sr;
        gload_lds16(A + (size_t)(m0 + row) * K + k0 + ssl, &lA[cs][c * 512]);
        gload_lds16(Bt + (size_t)(n0 + row) * K + k0 + ssl, &lB[cs][c * 512]);
      }
    }
    if (t >= 0) {
      const int cu = t & 1;
      s16x8 af[4], bf[4];
      #pragma unroll
      for (int i = 0; i < 4; ++i) af[i] = ld8(&lA[cu][aOff[i]]);
      #pragma unroll
      for (int i = 0; i < 4; ++i) bf[i] = ld8(&lB[cu][bOff[i]]);
      __builtin_amdgcn_s_setprio(1);
      #pragma unroll
      for (int mi = 0; mi < 4; ++mi)
        #pragma unroll
        for (int ni = 0; ni < 4; ++ni)
          acc[mi][ni] = __builtin_amdgcn_mfma_f32_16x16x32_bf16(af[mi], bf[ni], acc[mi][ni], 0, 0, 0);
      __builtin_amdgcn_s_setprio(0);
    }
    __syncthreads();  // full drain: tile t+1 landed, buffer reuse safe
  }
  #pragma unroll
  for (int mi = 0; mi < 4; ++mi) {
    #pragma unroll
    for (int ni = 0; ni < 4; ++ni) {
      const int row = m0 + wm + mi * 16 + lg * 4;
      const int col = n0 + wn + ni * 16 + lm;
      const float bs = bias[col];
      #pragma unroll
      for (int r = 0; r < 4; ++r) {
        float v = acc[mi][ni][r] + bs;
        if (OUT_BF16)
          ((unsigned short*)out)[(size_t)(row + r) * N + col] = f2bf(v);
        else
          ((float*)out)[(size_t)(row + r) * N + col] = v;
      }
    }
  }
}

// Flash attention, causal. Block-level queue: item = (bh, 64-row q-tile), LPT.
// r7-proven sync structure (stage -> compute -> __syncthreads). Adds T5
// setprio around MFMA clusters and T13 defer-max (skip O-rescale when the
// running max grows by <= 8; wave-uniform branch).
__global__ __launch_bounds__(256) void attn_kernel(
    const unsigned short* __restrict__ qkv,
    const unsigned short* __restrict__ vT,
    unsigned short* __restrict__ aout,
    int* __restrict__ ctr) {
  const int tid = threadIdx.x, lane = tid & 63, w = tid >> 6;
  const int lm = lane & 15, lg = lane >> 4;
  __shared__ unsigned short kbuf[2][64 * 128];  // [kv-row][128], slot-swizzled
  __shared__ unsigned short vbuf[2][128 * 64];  // [d][64], slot-swizzled
  __shared__ unsigned int pb[4][16 * 44];       // per-wave P rows, u32 stride 44
  __shared__ int s_item;
  const float scale = 0.08838834764831845f;  // 1/sqrt(128)
  unsigned int* pr = &pb[w][lm * 44];
  const int klg4 = lane >> 4, ks16 = lane & 15;  // K staging: row-in-4, slot
  const int vlg8 = lane >> 3, vs8 = lane & 7;    // V staging: d-in-8, slot
  for (;;) {
    __syncthreads();
    if (tid == 0) s_item = atomicAdd(ctr, 1);
    __syncthreads();
    const int item = s_item;
    if (item >= NITEMS) return;
    const int qt = 31 - (item / 24);  // expensive q-tiles first (LPT)
    const int bh = item % 24;
    const int b = bh / 6, h = bh % 6;
    const int q0 = qt * 64, wq0 = q0 + w * 16;
    const unsigned short* base = qkv + (size_t)b * SS * C3;
    const unsigned short* kg = base + CC + h * 128;
    const unsigned short* vg = vT + (size_t)bh * 128 * SS;
    s16x8 qf[4];
    {
      const unsigned short* qp = base + (size_t)(wq0 + lm) * C3 + h * 128 + lg * 8;
      #pragma unroll
      for (int ks = 0; ks < 4; ++ks) qf[ks] = ld8(qp + ks * 32);
    }
    f32x4 oacc[8] = {};
    float m_run = -1e30f, l_run = 0.0f;
    const int nt = qt + 1;  // 64-wide kv tiles
    #pragma unroll 1
    for (int t = -1; t < nt; ++t) {
      if (t + 1 < nt) {  // stage tile t+1 (K rows + V^T rows), inv-swizzled src
        const int n1 = (t + 1) * 64;
        const int cs = (t + 1) & 1;
        #pragma unroll
        for (int i = 0; i < 4; ++i) {
          int c = w * 4 + i;
          int r = c * 4 + klg4;
          gload_lds16(kg + (size_t)(n1 + r) * C3 + ((ks16 ^ (r & 7)) * 8),
                      &kbuf[cs][c * 512]);
        }
        #pragma unroll
        for (int i = 0; i < 4; ++i) {
          int c = w * 4 + i;
          int d = c * 8 + vlg8;
          gload_lds16(vg + (size_t)d * SS + n1 + ((vs8 ^ vlg8) * 8),
                      &vbuf[cs][c * 512]);
        }
      }
      if (t >= 0) {
        const int n0 = t * 64;
        const int cu = t & 1;
        const unsigned short* kb = kbuf[cu];
        const unsigned short* vb = vbuf[cu];
        // QK^T swapped: sacc[nsub] = S^T[n][q], n = n0+nsub*16+lg*4+r, q = lm
        f32x4 sacc[4] = {};
        __builtin_amdgcn_s_setprio(1);
        #pragma unroll
        for (int nsub = 0; nsub < 4; ++nsub) {
          const int kr = (nsub * 16 + lm) * 128;
          #pragma unroll
          for (int ks = 0; ks < 4; ++ks) {
            s16x8 kf = ld8(&kb[kr + (((ks * 4 + lg) ^ (lm & 7)) * 8)]);
            sacc[nsub] = __builtin_amdgcn_mfma_f32_16x16x32_bf16(kf, qf[ks], sacc[nsub], 0, 0, 0);
          }
        }
        __builtin_amdgcn_s_setprio(0);
        const int qg = wq0 + lm;
        const bool full = (n0 + 63 <= wq0);
        float xs[4][4];
        float tmax = -1e30f;
        #pragma unroll
        for (int nsub = 0; nsub < 4; ++nsub) {
          #pragma unroll
          for (int r = 0; r < 4; ++r) {
            int n = n0 + nsub * 16 + lg * 4 + r;
            float x = sacc[nsub][r] * scale;
            if (!full && n > qg) x = -1e30f;
            xs[nsub][r] = x;
            tmax = fmaxf(tmax, x);
          }
        }
        tmax = fmaxf(tmax, __shfl_xor(tmax, 16));
        tmax = fmaxf(tmax, __shfl_xor(tmax, 32));
        // T13 defer-max: skip rescale when max growth <= 8 (P bounded by e^8)
        const bool noresc = __all(tmax - m_run <= 8.0f);
        const float m_new = noresc ? m_run : fmaxf(m_run, tmax);
        float psum = 0.0f;
        unsigned int pk_[4][2];
        #pragma unroll
        for (int nsub = 0; nsub < 4; ++nsub) {
          float p0 = __expf(xs[nsub][0] - m_new);
          float p1 = __expf(xs[nsub][1] - m_new);
          float p2 = __expf(xs[nsub][2] - m_new);
          float p3 = __expf(xs[nsub][3] - m_new);
          psum += (p0 + p1) + (p2 + p3);
          pk_[nsub][0] = cvt_pk_bf16(p0, p1);
          pk_[nsub][1] = cvt_pk_bf16(p2, p3);
        }
        psum += __shfl_xor(psum, 16);
        psum += __shfl_xor(psum, 32);
        if (!noresc) {
          const float resc = __expf(m_run - m_new);
          l_run *= resc;
          m_run = m_new;
          float rs[4];
          #pragma unroll
          for (int r = 0; r < 4; ++r) rs[r] = __shfl(resc, lg * 4 + r);
          #pragma unroll
          for (int dsub = 0; dsub < 8; ++dsub)
            #pragma unroll
            for (int r = 0; r < 4; ++r) oacc[dsub][r] *= rs[r];
        }
        l_run += psum;
        // stage P^T -> P rows in per-wave LDS (uint2 = ds_write_b64)
        #pragma unroll
        for (int nsub = 0; nsub < 4; ++nsub) {
          uint2 pk2; pk2.x = pk_[nsub][0]; pk2.y = pk_[nsub][1];
          *reinterpret_cast<uint2*>(&pr[nsub * 8 + lg * 2]) = pk2;
        }
        // PV: A = P[q=lm][n-chunk], B = V^T frags from swizzled LDS
        __builtin_amdgcn_s_setprio(1);
        #pragma unroll
        for (int nch = 0; nch < 2; ++nch) {
          s16x8 pf = *reinterpret_cast<const s16x8*>(&pr[nch * 16 + lg * 4]);
          #pragma unroll
          for (int dsub = 0; dsub < 8; ++dsub) {
            const int vr = (dsub * 16 + lm) * 64;
            s16x8 vf = ld8(&vb[vr + (((nch * 4 + lg) ^ (lm & 7)) * 8)]);
            oacc[dsub] = __builtin_amdgcn_mfma_f32_16x16x32_bf16(pf, vf, oacc[dsub], 0, 0, 0);
          }
        }
        __builtin_amdgcn_s_setprio(0);
      }
      __syncthreads();  // full drain: tile t+1 landed, buffer reuse safe
    }
    float linv[4];
    #pragma unroll
    for (int r = 0; r < 4; ++r) linv[r] = 1.0f / __shfl(l_run, lg * 4 + r);
    #pragma unroll
    for (int dsub = 0; dsub < 8; ++dsub) {
      const int col = h * 128 + dsub * 16 + lm;
      #pragma unroll
      for (int r = 0; r < 4; ++r)
        aout[(size_t)(b * SS + wq0 + lg * 4 + r) * CC + col] =
            f2bf(oacc[dsub][r] * linv[r]);
    }
  }
}

extern "C" void kernel_launch(void* const* d_in, const int* in_sizes, int n_in,
                              void* d_out, int out_size, void* d_ws, size_t ws_size,
                              hipStream_t stream) {
  const float* x      = (const float*)d_in[0];
  const float* w_attn = (const float*)d_in[1];
  const float* b_attn = (const float*)d_in[2];
  const float* w_proj = (const float*)d_in[3];
  const float* b_proj = (const float*)d_in[4];
  float* out = (float*)d_out;

  const size_t M = 4 * (size_t)SS;  // 8192 tokens
  unsigned short* ws = (unsigned short*)d_ws;
  unsigned short* xb   = ws;                        // [8192,768] (dead after GEMM1)
  unsigned short* waT  = xb + M * CC;               // [2304,768]
  unsigned short* wpT  = waT + (size_t)C3 * CC;     // [768,768]
  unsigned short* qkv  = wpT + (size_t)CC * CC;     // [8192,2304]
  unsigned short* aout = qkv + M * C3;              // [8192,768]
  unsigned short* vT   = xb;                        // [24,128,2048] aliases dead xb
  int* ctr = (int*)(aout + M * CC);

  int n4 = (int)(M * CC / 4);
  cast_bf16_kernel<<<(n4 + 255) / 256, 256, 0, stream>>>(x, xb, n4);
  transpose_cast_kernel<<<dim3(C3 / 32, CC / 32), 256, 0, stream>>>(w_attn, waT, CC, C3);
  transpose_cast_kernel<<<dim3(CC / 32, CC / 32), 256, 0, stream>>>(w_proj, wpT, CC, CC);

  gemm_lds_kernel<1><<<dim3(C3 / 128, M / 128), 256, 0, stream>>>(
      xb, waT, b_attn, (void*)qkv, (int)M, C3, CC);

  vtrans_kernel<<<dim3(SS / 64, 24), 256, 0, stream>>>(qkv, vT);

  hipMemsetAsync(ctr, 0, sizeof(int), stream);
  attn_kernel<<<512, 256, 0, stream>>>(qkv, vT, aout, ctr);

  gemm_lds_kernel<0><<<dim3(CC / 128, M / 128), 256, 0, stream>>>(
      aout, wpT, b_proj, (void*)out, (int)M, CC, CC);
}

// Round 10
// 158.140 us; speedup vs baseline: 2.1087x; 1.2355x over previous
//
#include <hip/hip_runtime.h>
#include <hip/hip_bf16.h>
#include <stdint.h>

// CausalMultiHeadAttention: B=4 S=2048 C=768 H=6 D=128
// cast(x,wT) -> GEMM1(counted-vmcnt 2-buf pipeline) -> V-transpose ->
// flash-attn(block queue, counted-vmcnt 2-buf pipeline) -> GEMM2
#define SS 2048
#define CC 768
#define C3 2304
#define NITEMS (32 * 24)  // 64-row q-tiles x (b,h)

typedef float f32x4 __attribute__((ext_vector_type(4)));
typedef short s16x8 __attribute__((ext_vector_type(8)));

__device__ __forceinline__ unsigned short f2bf(float f) {
  union { float f; unsigned int u; } v; v.f = f;
  unsigned int r = (v.u + 0x7FFFu + ((v.u >> 16) & 1u)) >> 16;
  return (unsigned short)r;
}

__device__ __forceinline__ s16x8 ld8(const unsigned short* p) {
  return *reinterpret_cast<const s16x8*>(p);
}

__device__ __forceinline__ unsigned int cvt_pk_bf16(float lo, float hi) {
  unsigned int r;
  asm("v_cvt_pk_bf16_f32 %0, %1, %2" : "=v"(r) : "v"(lo), "v"(hi));
  return r;
}

// async global->LDS, 16B/lane. LDS dest = wave-uniform base + lane*16 (linear);
// per-lane global src carries the swizzle (rule #21: linear dest + inv-swz src).
__device__ __forceinline__ void gload_lds16(const unsigned short* g, unsigned short* l) {
  __builtin_amdgcn_global_load_lds(
      (const __attribute__((address_space(1))) void*)g,
      (__attribute__((address_space(3))) void*)l, 16, 0, 0);
}

__global__ __launch_bounds__(256) void cast_bf16_kernel(
    const float* __restrict__ src, unsigned short* __restrict__ dst, int n4) {
  int i = blockIdx.x * 256 + threadIdx.x;
  if (i < n4) {
    float4 v = reinterpret_cast<const float4*>(src)[i];
    ushort4 o;
    o.x = f2bf(v.x); o.y = f2bf(v.y); o.z = f2bf(v.z); o.w = f2bf(v.w);
    reinterpret_cast<ushort4*>(dst)[i] = o;
  }
}

// src [R][C] f32 -> dst [C][R] bf16
__global__ __launch_bounds__(256) void transpose_cast_kernel(
    const float* __restrict__ src, unsigned short* __restrict__ dst, int R, int C) {
  __shared__ float tile[32][33];
  int c0 = blockIdx.x * 32, r0 = blockIdx.y * 32;
  int tx = threadIdx.x & 31, ty = threadIdx.x >> 5;
  #pragma unroll
  for (int i = 0; i < 32; i += 8)
    tile[ty + i][tx] = src[(size_t)(r0 + ty + i) * C + c0 + tx];
  __syncthreads();
  #pragma unroll
  for (int i = 0; i < 32; i += 8)
    dst[(size_t)(c0 + ty + i) * R + r0 + tx] = f2bf(tile[tx][ty + i]);
}

// V region of qkv [token][C3] -> vT [bh][d=128][n=S], 64x128 tiles via swizzled LDS
__global__ __launch_bounds__(256) void vtrans_kernel(
    const unsigned short* __restrict__ qkv, unsigned short* __restrict__ vT) {
  __shared__ unsigned short t[64 * 128];
  const int tid = threadIdx.x;
  const int n0 = blockIdx.x * 64;
  const int bh = blockIdx.y;
  const int b = bh / 6, h = bh % 6;
  #pragma unroll
  for (int it = 0; it < 4; ++it) {
    int c = it * 256 + tid;
    int n = c >> 4, slot = c & 15;
    s16x8 v = ld8(qkv + (size_t)(b * SS + n0 + n) * C3 + 2 * CC + h * 128 + slot * 8);
    int ss = slot ^ ((n >> 3) & 7);
    *reinterpret_cast<s16x8*>(&t[n * 128 + ss * 8]) = v;
  }
  __syncthreads();
  #pragma unroll
  for (int it = 0; it < 4; ++it) {
    int c = it * 256 + tid;
    int d = c >> 3, n8 = (c & 7) * 8;
    s16x8 o;
    #pragma unroll
    for (int j = 0; j < 8; ++j) {
      int n = n8 + j;
      int sl = (d >> 3) ^ ((n >> 3) & 7);
      o[j] = (short)t[n * 128 + sl * 8 + (d & 7)];
    }
    *reinterpret_cast<s16x8*>(&vT[((size_t)bh * 128 + d) * SS + n0 + n8]) = o;
  }
}

// C[m][n] = sum_k A[m][k]*Bt[n][k] + bias[n]. 128x128 tile, BK=32, 2 LDS bufs.
// T3/T4 counted-vmcnt pipeline, per K-step:
//   stage(t+1) -> s_waitcnt vmcnt(4) [t landed, t+1 in flight] -> s_barrier ->
//   compute(t) -> lgkmcnt(0) -> s_barrier  [releases buf (t)&1 for stage(t+2)]
// WAR proof: stage(t+1) writes buf (t+1)&1, last read by compute(t-1), whose
// reads were retired before the end-barrier of iter t-1 (lgkmcnt(0) fence).
template <int OUT_BF16>
__global__ __launch_bounds__(256) void gemm_lds_kernel(
    const unsigned short* __restrict__ A, const unsigned short* __restrict__ Bt,
    const float* __restrict__ bias, void* __restrict__ out, int M, int N, int K) {
  __shared__ unsigned short lA[2][128 * 32];
  __shared__ unsigned short lB[2][128 * 32];
  const int tid = threadIdx.x, lane = tid & 63, w = tid >> 6;
  // XCD-bijective swizzle (nwg % 8 == 0 for all our grids)
  const int nbx = gridDim.x;
  int bid = blockIdx.y * nbx + blockIdx.x;
  const int cpx = (nbx * gridDim.y) >> 3;
  bid = (bid & 7) * cpx + (bid >> 3);
  const int m0 = (bid / nbx) * 128, n0 = (bid % nbx) * 128;
  const int lm = lane & 15, lg = lane >> 4;
  const int wm = (w >> 1) * 64, wn = (w & 1) * 64;
  const int sr = lane >> 2;                            // row-in-chunk 0..15
  const int ssl = ((lane & 3) ^ ((sr >> 1) & 3)) * 8;  // inv-swizzled k-slot
  int aOff[4], bOff[4];
  #pragma unroll
  for (int i = 0; i < 4; ++i) {
    int ra = wm + i * 16 + lm, rb = wn + i * 16 + lm;
    aOff[i] = ra * 32 + ((lg ^ ((ra >> 1) & 3)) * 8);
    bOff[i] = rb * 32 + ((lg ^ ((rb >> 1) & 3)) * 8);
  }
  f32x4 acc[4][4] = {};
  const int nt = K / 32;
  #define GSTAGE(tt, bb)                                                      \
    {                                                                         \
      const int k0_ = (tt) * 32;                                              \
      _Pragma("unroll")                                                       \
      for (int i_ = 0; i_ < 2; ++i_) {                                        \
        int c_ = w * 2 + i_;                                                  \
        int row_ = c_ * 16 + sr;                                              \
        gload_lds16(A + (size_t)(m0 + row_) * K + k0_ + ssl, &lA[bb][c_ * 512]); \
        gload_lds16(Bt + (size_t)(n0 + row_) * K + k0_ + ssl, &lB[bb][c_ * 512]); \
      }                                                                       \
    }
  GSTAGE(0, 0);
  #pragma unroll 1
  for (int t = 0; t < nt; ++t) {
    if (t + 1 < nt) {
      GSTAGE(t + 1, (t + 1) & 1);                       // 4 more in flight
      asm volatile("s_waitcnt vmcnt(4)" ::: "memory");  // tile t landed
    } else {
      asm volatile("s_waitcnt vmcnt(0)" ::: "memory");  // last tile landed
    }
    __builtin_amdgcn_sched_barrier(0);
    __builtin_amdgcn_s_barrier();   // all waves' chunks of tile t visible
    const int cu = t & 1;
    s16x8 af[4], bf[4];
    #pragma unroll
    for (int i = 0; i < 4; ++i) af[i] = ld8(&lA[cu][aOff[i]]);
    #pragma unroll
    for (int i = 0; i < 4; ++i) bf[i] = ld8(&lB[cu][bOff[i]]);
    __builtin_amdgcn_s_setprio(1);
    #pragma unroll
    for (int mi = 0; mi < 4; ++mi)
      #pragma unroll
      for (int ni = 0; ni < 4; ++ni)
        acc[mi][ni] = __builtin_amdgcn_mfma_f32_16x16x32_bf16(af[mi], bf[ni], acc[mi][ni], 0, 0, 0);
    __builtin_amdgcn_s_setprio(0);
    asm volatile("s_waitcnt lgkmcnt(0)" ::: "memory");  // LDS reads retired
    __builtin_amdgcn_sched_barrier(0);                  // rule #18 fence
    __builtin_amdgcn_s_barrier();   // release buf t&1 for stage(t+2)
  }
  #pragma unroll
  for (int mi = 0; mi < 4; ++mi) {
    #pragma unroll
    for (int ni = 0; ni < 4; ++ni) {
      const int row = m0 + wm + mi * 16 + lg * 4;
      const int col = n0 + wn + ni * 16 + lm;
      const float bs = bias[col];
      #pragma unroll
      for (int r = 0; r < 4; ++r) {
        float v = acc[mi][ni][r] + bs;
        if (OUT_BF16)
          ((unsigned short*)out)[(size_t)(row + r) * N + col] = f2bf(v);
        else
          ((float*)out)[(size_t)(row + r) * N + col] = v;
      }
    }
  }
  #undef GSTAGE
}

// Flash attention, causal. Block-level queue: item = (bh, 64-row q-tile), LPT.
// Same counted-vmcnt 2-buf pipeline as the GEMM (8 stage-loads/thread ->
// vmcnt(8) steady state, vmcnt(0) on the last tile). setprio + defer-max kept.
__global__ __launch_bounds__(256) void attn_kernel(
    const unsigned short* __restrict__ qkv,
    const unsigned short* __restrict__ vT,
    unsigned short* __restrict__ aout,
    int* __restrict__ ctr) {
  const int tid = threadIdx.x, lane = tid & 63, w = tid >> 6;
  const int lm = lane & 15, lg = lane >> 4;
  __shared__ unsigned short kbuf[2][64 * 128];  // [kv-row][128], slot-swizzled
  __shared__ unsigned short vbuf[2][128 * 64];  // [d][64], slot-swizzled
  __shared__ unsigned int pb[4][16 * 44];       // per-wave P rows, u32 stride 44
  __shared__ int s_item;
  const float scale = 0.08838834764831845f;  // 1/sqrt(128)
  unsigned int* pr = &pb[w][lm * 44];
  const int klg4 = lane >> 4, ks16 = lane & 15;  // K staging: row-in-4, slot
  const int vlg8 = lane >> 3, vs8 = lane & 7;    // V staging: d-in-8, slot
  for (;;) {
    __syncthreads();
    if (tid == 0) s_item = atomicAdd(ctr, 1);
    __syncthreads();
    const int item = s_item;
    if (item >= NITEMS) return;
    const int qt = 31 - (item / 24);  // expensive q-tiles first (LPT)
    const int bh = item % 24;
    const int b = bh / 6, h = bh % 6;
    const int q0 = qt * 64, wq0 = q0 + w * 16;
    const unsigned short* base = qkv + (size_t)b * SS * C3;
    const unsigned short* kg = base + CC + h * 128;
    const unsigned short* vg = vT + (size_t)bh * 128 * SS;
    s16x8 qf[4];
    {
      const unsigned short* qp = base + (size_t)(wq0 + lm) * C3 + h * 128 + lg * 8;
      #pragma unroll
      for (int ks = 0; ks < 4; ++ks) qf[ks] = ld8(qp + ks * 32);
    }
    #define ASTAGE(tt, bb)                                                    \
      {                                                                       \
        const int n1_ = (tt) * 64;                                            \
        _Pragma("unroll")                                                     \
        for (int i_ = 0; i_ < 4; ++i_) {                                      \
          int c_ = w * 4 + i_;                                                \
          int r_ = c_ * 4 + klg4;                                             \
          gload_lds16(kg + (size_t)(n1_ + r_) * C3 + ((ks16 ^ (r_ & 7)) * 8), \
                      &kbuf[bb][c_ * 512]);                                   \
        }                                                                     \
        _Pragma("unroll")                                                     \
        for (int i_ = 0; i_ < 4; ++i_) {                                      \
          int c_ = w * 4 + i_;                                                \
          int d_ = c_ * 8 + vlg8;                                             \
          gload_lds16(vg + (size_t)d_ * SS + n1_ + ((vs8 ^ vlg8) * 8),        \
                      &vbuf[bb][c_ * 512]);                                   \
        }                                                                     \
      }
    f32x4 oacc[8] = {};
    float m_run = -1e30f, l_run = 0.0f;
    const int nt = qt + 1;  // 64-wide kv tiles
    ASTAGE(0, 0);
    #pragma unroll 1
    for (int t = 0; t < nt; ++t) {
      if (t + 1 < nt) {
        ASTAGE(t + 1, (t + 1) & 1);                       // 8 more in flight
        asm volatile("s_waitcnt vmcnt(8)" ::: "memory");  // tile t landed
      } else {
        asm volatile("s_waitcnt vmcnt(0)" ::: "memory");
      }
      __builtin_amdgcn_sched_barrier(0);
      __builtin_amdgcn_s_barrier();   // all waves' chunks of tile t visible
      const int n0 = t * 64;
      const int cu = t & 1;
      const unsigned short* kb = kbuf[cu];
      const unsigned short* vb = vbuf[cu];
      // QK^T swapped: sacc[nsub] = S^T[n][q], n = n0+nsub*16+lg*4+r, q = lm
      f32x4 sacc[4] = {};
      __builtin_amdgcn_s_setprio(1);
      #pragma unroll
      for (int nsub = 0; nsub < 4; ++nsub) {
        const int kr = (nsub * 16 + lm) * 128;
        #pragma unroll
        for (int ks = 0; ks < 4; ++ks) {
          s16x8 kf = ld8(&kb[kr + (((ks * 4 + lg) ^ (lm & 7)) * 8)]);
          sacc[nsub] = __builtin_amdgcn_mfma_f32_16x16x32_bf16(kf, qf[ks], sacc[nsub], 0, 0, 0);
        }
      }
      __builtin_amdgcn_s_setprio(0);
      const int qg = wq0 + lm;
      const bool full = (n0 + 63 <= wq0);
      float xs[4][4];
      float tmax = -1e30f;
      #pragma unroll
      for (int nsub = 0; nsub < 4; ++nsub) {
        #pragma unroll
        for (int r = 0; r < 4; ++r) {
          int n = n0 + nsub * 16 + lg * 4 + r;
          float x = sacc[nsub][r] * scale;
          if (!full && n > qg) x = -1e30f;
          xs[nsub][r] = x;
          tmax = fmaxf(tmax, x);
        }
      }
      tmax = fmaxf(tmax, __shfl_xor(tmax, 16));
      tmax = fmaxf(tmax, __shfl_xor(tmax, 32));
      // T13 defer-max: skip rescale when max growth <= 8 (P bounded by e^8)
      const bool noresc = __all(tmax - m_run <= 8.0f);
      const float m_new = noresc ? m_run : fmaxf(m_run, tmax);
      float psum = 0.0f;
      unsigned int pk_[4][2];
      #pragma unroll
      for (int nsub = 0; nsub < 4; ++nsub) {
        float p0 = __expf(xs[nsub][0] - m_new);
        float p1 = __expf(xs[nsub][1] - m_new);
        float p2 = __expf(xs[nsub][2] - m_new);
        float p3 = __expf(xs[nsub][3] - m_new);
        psum += (p0 + p1) + (p2 + p3);
        pk_[nsub][0] = cvt_pk_bf16(p0, p1);
        pk_[nsub][1] = cvt_pk_bf16(p2, p3);
      }
      psum += __shfl_xor(psum, 16);
      psum += __shfl_xor(psum, 32);
      if (!noresc) {
        const float resc = __expf(m_run - m_new);
        l_run *= resc;
        m_run = m_new;
        float rs[4];
        #pragma unroll
        for (int r = 0; r < 4; ++r) rs[r] = __shfl(resc, lg * 4 + r);
        #pragma unroll
        for (int dsub = 0; dsub < 8; ++dsub)
          #pragma unroll
          for (int r = 0; r < 4; ++r) oacc[dsub][r] *= rs[r];
      }
      l_run += psum;
      // stage P^T -> P rows in per-wave LDS (uint2 = ds_write_b64)
      #pragma unroll
      for (int nsub = 0; nsub < 4; ++nsub) {
        uint2 pk2; pk2.x = pk_[nsub][0]; pk2.y = pk_[nsub][1];
        *reinterpret_cast<uint2*>(&pr[nsub * 8 + lg * 2]) = pk2;
      }
      // PV: A = P[q=lm][n-chunk], B = V^T frags from swizzled LDS
      __builtin_amdgcn_s_setprio(1);
      #pragma unroll
      for (int nch = 0; nch < 2; ++nch) {
        s16x8 pf = *reinterpret_cast<const s16x8*>(&pr[nch * 16 + lg * 4]);
        #pragma unroll
        for (int dsub = 0; dsub < 8; ++dsub) {
          const int vr = (dsub * 16 + lm) * 64;
          s16x8 vf = ld8(&vb[vr + (((nch * 4 + lg) ^ (lm & 7)) * 8)]);
          oacc[dsub] = __builtin_amdgcn_mfma_f32_16x16x32_bf16(pf, vf, oacc[dsub], 0, 0, 0);
        }
      }
      __builtin_amdgcn_s_setprio(0);
      asm volatile("s_waitcnt lgkmcnt(0)" ::: "memory");  // LDS reads retired
      __builtin_amdgcn_sched_barrier(0);                  // rule #18 fence
      __builtin_amdgcn_s_barrier();   // release buf t&1 for stage(t+2)
    }
    #undef ASTAGE
    float linv[4];
    #pragma unroll
    for (int r = 0; r < 4; ++r) linv[r] = 1.0f / __shfl(l_run, lg * 4 + r);
    #pragma unroll
    for (int dsub = 0; dsub < 8; ++dsub) {
      const int col = h * 128 + dsub * 16 + lm;
      #pragma unroll
      for (int r = 0; r < 4; ++r)
        aout[(size_t)(b * SS + wq0 + lg * 4 + r) * CC + col] =
            f2bf(oacc[dsub][r] * linv[r]);
    }
  }
}

extern "C" void kernel_launch(void* const* d_in, const int* in_sizes, int n_in,
                              void* d_out, int out_size, void* d_ws, size_t ws_size,
                              hipStream_t stream) {
  const float* x      = (const float*)d_in[0];
  const float* w_attn = (const float*)d_in[1];
  const float* b_attn = (const float*)d_in[2];
  const float* w_proj = (const float*)d_in[3];
  const float* b_proj = (const float*)d_in[4];
  float* out = (float*)d_out;

  const size_t M = 4 * (size_t)SS;  // 8192 tokens
  unsigned short* ws = (unsigned short*)d_ws;
  unsigned short* xb   = ws;                        // [8192,768] (dead after GEMM1)
  unsigned short* waT  = xb + M * CC;               // [2304,768]
  unsigned short* wpT  = waT + (size_t)C3 * CC;     // [768,768]
  unsigned short* qkv  = wpT + (size_t)CC * CC;     // [8192,2304]
  unsigned short* aout = qkv + M * C3;              // [8192,768]
  unsigned short* vT   = xb;                        // [24,128,2048] aliases dead xb
  int* ctr = (int*)(aout + M * CC);

  int n4 = (int)(M * CC / 4);
  cast_bf16_kernel<<<(n4 + 255) / 256, 256, 0, stream>>>(x, xb, n4);
  transpose_cast_kernel<<<dim3(C3 / 32, CC / 32), 256, 0, stream>>>(w_attn, waT, CC, C3);
  transpose_cast_kernel<<<dim3(CC / 32, CC / 32), 256, 0, stream>>>(w_proj, wpT, CC, CC);

  gemm_lds_kernel<1><<<dim3(C3 / 128, M / 128), 256, 0, stream>>>(
      xb, waT, b_attn, (void*)qkv, (int)M, C3, CC);

  vtrans_kernel<<<dim3(SS / 64, 24), 256, 0, stream>>>(qkv, vT);

  hipMemsetAsync(ctr, 0, sizeof(int), stream);
  attn_kernel<<<512, 256, 0, stream>>>(qkv, vT, aout, ctr);

  gemm_lds_kernel<0><<<dim3(CC / 128, M / 128), 256, 0, stream>>>(
      aout, wpT, b_proj, (void*)out, (int)M, CC, CC);
}